// Round 6
// baseline (68.701 us; speedup 1.0000x reference)
//
#include <hip/hip_runtime.h>

#define NB 32
#define TT 4096
#define DD 768
#define NJ 64
#define CHUNK 32
#define CPD (TT / CHUNK)          // 128 chunks per doc
#define NCLAUSES (NB * NJ)

typedef float f4 __attribute__((ext_vector_type(4)));

__device__ __forceinline__ void dot_pair(
    const f4 h0, const f4 h1, const f4 h2,
    const f4 wf0, const f4 wf1, const f4 wf2,
    const f4 we0, const f4 we1, const f4 we2,
    float& pf, float& pe)
{
    pf = h0.x * wf0.x;
    pf = fmaf(h0.y, wf0.y, pf); pf = fmaf(h0.z, wf0.z, pf); pf = fmaf(h0.w, wf0.w, pf);
    pf = fmaf(h1.x, wf1.x, pf); pf = fmaf(h1.y, wf1.y, pf);
    pf = fmaf(h1.z, wf1.z, pf); pf = fmaf(h1.w, wf1.w, pf);
    pf = fmaf(h2.x, wf2.x, pf); pf = fmaf(h2.y, wf2.y, pf);
    pf = fmaf(h2.z, wf2.z, pf); pf = fmaf(h2.w, wf2.w, pf);

    pe = h0.x * we0.x;
    pe = fmaf(h0.y, we0.y, pe); pe = fmaf(h0.z, we0.z, pe); pe = fmaf(h0.w, we0.w, pe);
    pe = fmaf(h1.x, we1.x, pe); pe = fmaf(h1.y, we1.y, pe);
    pe = fmaf(h1.z, we1.z, pe); pe = fmaf(h1.w, we1.w, pe);
    pe = fmaf(h2.x, we2.x, pe); pe = fmaf(h2.y, we2.y, pe);
    pe = fmaf(h2.z, we2.z, pe); pe = fmaf(h2.w, we2.w, pe);
}

__device__ __forceinline__ void reduce_pair(float& pf, float& pe)
{
    #pragma unroll
    for (int s = 1; s < 64; s <<= 1) {
        pf += __shfl_xor(pf, s, 64);
        pe += __shfl_xor(pe, s, 64);
    }
}

// Device-coherent (sc1) scalar store/load: visible across XCDs once vmcnt
// retires — no buffer_wbl2 L2 flush needed (that was R4's 7x blowup).
__device__ __forceinline__ void store_coherent(float* p, float v) {
    __hip_atomic_store(p, v, __ATOMIC_RELAXED, __HIP_MEMORY_SCOPE_AGENT);
}
__device__ __forceinline__ float load_coherent(const float* p) {
    return __hip_atomic_load(p, __ATOMIC_RELAXED, __HIP_MEMORY_SCOPE_AGENT);
}

// Fused: streaming per-token dual dots (sc1 scalar results -> ws); the last
// block of each doc (per-doc relaxed agent atomic counter; __syncthreads'
// vmcnt(0) drain orders the sc1 stores before the atomic) pools all 64
// clauses of that doc. Deterministic: out depends only on completed ws.
__global__ __launch_bounds__(256) void fused_kernel(
    const float* __restrict__ hs,         // [B, T, D]
    const int*   __restrict__ clause_len, // [B, J]
    const float* __restrict__ fc_w,       // [D]
    const float* __restrict__ fc_b,       // [1]
    const float* __restrict__ emo_w,      // [D]
    const float* __restrict__ emo_b,      // [1]
    float*       __restrict__ out,        // [B, J]
    float*       __restrict__ ws_fc,      // [B, T]
    float*       __restrict__ ws_emo,     // [B, T]
    int*         __restrict__ done)       // [B] zeroed per call
{
    const int g     = blockIdx.x;
    const int b     = g & (NB - 1);       // doc-minor: uniform resident load
    const int chunk = g >> 5;
    const int lane  = threadIdx.x & 63;
    const int wave  = threadIdx.x >> 6;

    const int cl = clause_len[(b << 6) + lane];
    int L = cl;
    #pragma unroll
    for (int s = 1; s < 64; s <<= 1) L += __shfl_xor(L, s, 64);

    const int r0 = chunk * CHUNK + (wave << 3);
    const int nr = min(8, L - r0);

    if (nr > 0) {
        const f4* fw4 = (const f4*)fc_w;
        const f4* ew4 = (const f4*)emo_w;
        const f4 wf0 = fw4[lane], wf1 = fw4[lane + 64], wf2 = fw4[lane + 128];
        const f4 we0 = ew4[lane], we1 = ew4[lane + 64], we2 = ew4[lane + 128];

        const f4* r4  = (const f4*)(hs + ((size_t)b * TT + r0) * DD);
        float*    ofc = ws_fc  + b * TT + r0;
        float*    oem = ws_emo + b * TT + r0;

        if (nr == 8) {
            f4 a0 = r4[lane], a1 = r4[lane + 64], a2 = r4[lane + 128];
            #pragma unroll
            for (int i = 0; i < 8; ++i) {
                float pf, pe;
                if (i < 7) {
                    const f4* n4 = r4 + (i + 1) * 192;
                    const f4 b0 = n4[lane], b1 = n4[lane + 64], b2 = n4[lane + 128];
                    dot_pair(a0, a1, a2, wf0, wf1, wf2, we0, we1, we2, pf, pe);
                    reduce_pair(pf, pe);
                    if (lane == 0) { store_coherent(ofc + i, pf); store_coherent(oem + i, pe); }
                    a0 = b0; a1 = b1; a2 = b2;
                } else {
                    dot_pair(a0, a1, a2, wf0, wf1, wf2, we0, we1, we2, pf, pe);
                    reduce_pair(pf, pe);
                    if (lane == 0) { store_coherent(ofc + i, pf); store_coherent(oem + i, pe); }
                }
            }
        } else {
            for (int i = 0; i < nr; ++i) {
                const f4* n4 = r4 + i * 192;
                const f4 a0 = n4[lane], a1 = n4[lane + 64], a2 = n4[lane + 128];
                float pf, pe;
                dot_pair(a0, a1, a2, wf0, wf1, wf2, we0, we1, we2, pf, pe);
                reduce_pair(pf, pe);
                if (lane == 0) { store_coherent(ofc + i, pf); store_coherent(oem + i, pe); }
            }
        }
    }

    // ---- completion protocol: syncthreads drains each wave's vmcnt(0)
    // (sc1 stores globally visible), then one relaxed agent-scope RMW.
    __syncthreads();
    __shared__ int s_win;
    if (threadIdx.x == 0) {
        const int old = __hip_atomic_fetch_add(done + b, 1, __ATOMIC_RELAXED,
                                               __HIP_MEMORY_SCOPE_AGENT);
        s_win = (old == CPD - 1) ? 1 : 0;
    }
    __syncthreads();
    if (!s_win) return;

    // ---- winner: pool all 64 clauses of doc b (logic proven in R4) ----
    int incl = cl;
    #pragma unroll
    for (int s = 1; s < 64; s <<= 1) {
        int v = __shfl_up(incl, s, 64);
        if (lane >= s) incl += v;
    }
    const int excl = incl - cl;
    const float fcb = fc_b[0], emb = emo_b[0];

    for (int j = wave; j < NJ; j += 4) {
        const int clen = __shfl(cl, j, 64);
        const int st   = __shfl(excl, j, 64);
        const bool valid = lane < clen;
        const int  t     = b * TT + st + lane;
        float v   = valid ? (load_coherent(ws_fc + t) + fcb) : -3.0e38f;
        float sem = valid ? load_coherent(ws_emo + t) : 0.0f;
        float m = v;
        #pragma unroll
        for (int s = 1; s < 64; s <<= 1) m = fmaxf(m, __shfl_xor(m, s, 64));
        const float e = valid ? __expf(v - m) : 0.0f;
        float Z = e, S = e * sem;
        #pragma unroll
        for (int s = 1; s < 64; s <<= 1) {
            Z += __shfl_xor(Z, s, 64);
            S += __shfl_xor(S, s, 64);
        }
        if (lane == 0) {
            const float logit = S / Z + emb;
            out[(b << 6) + j] = 1.0f / (1.0f + __expf(-logit));
        }
    }
}

// ---------------- Fallback two-kernel path (ws too small) ------------------
__global__ __launch_bounds__(256) void pool_kernel(
    const int*   __restrict__ clause_len,
    const float* __restrict__ ws_fc,
    const float* __restrict__ ws_emo,
    const float* __restrict__ fc_b,
    const float* __restrict__ emo_b,
    float*       __restrict__ out)
{
    const int lane = threadIdx.x & 63;
    const int wave = threadIdx.x >> 6;
    const int bj   = (blockIdx.x << 2) + wave;
    const int b    = bj >> 6;
    const int j    = bj & 63;

    const int cl   = clause_len[(b << 6) + lane];
    const int clen = __shfl(cl, j, 64);
    int pre = (lane < j) ? cl : 0;
    #pragma unroll
    for (int s = 1; s < 64; s <<= 1) pre += __shfl_xor(pre, s, 64);
    const int start = pre;

    const bool valid = lane < clen;
    const int  t     = b * TT + start + lane;
    float v   = valid ? (ws_fc[t] + fc_b[0]) : -3.0e38f;
    float sem = valid ? ws_emo[t] : 0.0f;
    float m = v;
    #pragma unroll
    for (int s = 1; s < 64; s <<= 1) m = fmaxf(m, __shfl_xor(m, s, 64));
    const float e = valid ? __expf(v - m) : 0.0f;
    float Z = e, S = e * sem;
    #pragma unroll
    for (int s = 1; s < 64; s <<= 1) {
        Z += __shfl_xor(Z, s, 64);
        S += __shfl_xor(S, s, 64);
    }
    if (lane == 0) {
        const float logit = S / Z + emo_b[0];
        out[bj] = 1.0f / (1.0f + __expf(-logit));
    }
}

__global__ __launch_bounds__(256) void dots_kernel(
    const float* __restrict__ hs,
    const int*   __restrict__ clause_len,
    const float* __restrict__ fc_w,
    const float* __restrict__ emo_w,
    float*       __restrict__ ws_fc,
    float*       __restrict__ ws_emo)
{
    const int g     = blockIdx.x;
    const int b     = g & (NB - 1);
    const int chunk = g >> 5;
    const int lane  = threadIdx.x & 63;
    const int wave  = threadIdx.x >> 6;

    int L = clause_len[(b << 6) + lane];
    #pragma unroll
    for (int s = 1; s < 64; s <<= 1) L += __shfl_xor(L, s, 64);

    const int r0 = chunk * CHUNK + (wave << 3);
    const int nr = min(8, L - r0);
    if (nr <= 0) return;

    const f4* fw4 = (const f4*)fc_w;
    const f4* ew4 = (const f4*)emo_w;
    const f4 wf0 = fw4[lane], wf1 = fw4[lane + 64], wf2 = fw4[lane + 128];
    const f4 we0 = ew4[lane], we1 = ew4[lane + 64], we2 = ew4[lane + 128];

    const f4* r4  = (const f4*)(hs + ((size_t)b * TT + r0) * DD);
    float*    ofc = ws_fc  + b * TT + r0;
    float*    oem = ws_emo + b * TT + r0;

    for (int i = 0; i < nr; ++i) {
        const f4* n4 = r4 + i * 192;
        const f4 a0 = n4[lane], a1 = n4[lane + 64], a2 = n4[lane + 128];
        float pf, pe;
        dot_pair(a0, a1, a2, wf0, wf1, wf2, we0, we1, we2, pf, pe);
        reduce_pair(pf, pe);
        if (lane == 0) { ofc[i] = pf; oem[i] = pe; }
    }
}

extern "C" void kernel_launch(void* const* d_in, const int* in_sizes, int n_in,
                              void* d_out, int out_size, void* d_ws, size_t ws_size,
                              hipStream_t stream) {
    const float* hs         = (const float*)d_in[0];
    const int*   clause_len = (const int*)d_in[1];
    const float* fc_w       = (const float*)d_in[2];
    const float* fc_b       = (const float*)d_in[3];
    const float* emo_w      = (const float*)d_in[4];
    const float* emo_b      = (const float*)d_in[5];
    float* out = (float*)d_out;

    float* ws_fc  = (float*)d_ws;                  // [B*T]
    float* ws_emo = ws_fc + NB * TT;               // [B*T]
    const size_t base_bytes = (size_t)2 * NB * TT * sizeof(float);  // 1 MiB

    if (ws_size >= base_bytes + NB * sizeof(int)) {
        int* done = (int*)((char*)d_ws + base_bytes);
        hipMemsetAsync(done, 0, NB * sizeof(int), stream);
        fused_kernel<<<NB * CPD, 256, 0, stream>>>(
            hs, clause_len, fc_w, fc_b, emo_w, emo_b, out, ws_fc, ws_emo, done);
    } else {
        dots_kernel<<<NB * CPD, 256, 0, stream>>>(
            hs, clause_len, fc_w, emo_w, ws_fc, ws_emo);
        pool_kernel<<<NCLAUSES / 4, 256, 0, stream>>>(
            clause_len, ws_fc, ws_emo, fc_b, emo_b, out);
    }
}

// Round 7
// 41.846 us; speedup vs baseline: 1.6418x; 1.6418x over previous
//
#include <hip/hip_runtime.h>

#define NB 32
#define TT 4096
#define DD 768
#define NJ 64
#define CHUNK 64
#define CPD (TT / CHUNK)          // 64 chunks per doc -> grid 2048, uniform
#define NCLAUSES (NB * NJ)

typedef float f4 __attribute__((ext_vector_type(4)));

__device__ __forceinline__ void dot_pair(
    const f4 h0, const f4 h1, const f4 h2,
    const f4 wf0, const f4 wf1, const f4 wf2,
    const f4 we0, const f4 we1, const f4 we2,
    float& pf, float& pe)
{
    pf = h0.x * wf0.x;
    pf = fmaf(h0.y, wf0.y, pf); pf = fmaf(h0.z, wf0.z, pf); pf = fmaf(h0.w, wf0.w, pf);
    pf = fmaf(h1.x, wf1.x, pf); pf = fmaf(h1.y, wf1.y, pf);
    pf = fmaf(h1.z, wf1.z, pf); pf = fmaf(h1.w, wf1.w, pf);
    pf = fmaf(h2.x, wf2.x, pf); pf = fmaf(h2.y, wf2.y, pf);
    pf = fmaf(h2.z, wf2.z, pf); pf = fmaf(h2.w, wf2.w, pf);

    pe = h0.x * we0.x;
    pe = fmaf(h0.y, we0.y, pe); pe = fmaf(h0.z, we0.z, pe); pe = fmaf(h0.w, we0.w, pe);
    pe = fmaf(h1.x, we1.x, pe); pe = fmaf(h1.y, we1.y, pe);
    pe = fmaf(h1.z, we1.z, pe); pe = fmaf(h1.w, we1.w, pe);
    pe = fmaf(h2.x, we2.x, pe); pe = fmaf(h2.y, we2.y, pe);
    pe = fmaf(h2.z, we2.z, pe); pe = fmaf(h2.w, we2.w, pe);
}

__device__ __forceinline__ void reduce_pair(float& pf, float& pe)
{
    #pragma unroll
    for (int s = 1; s < 64; s <<= 1) {
        pf += __shfl_xor(pf, s, 64);
        pe += __shfl_xor(pe, s, 64);
    }
}

// ---------------- Phase 1: per-token dual dot-products --------------------
// Grid = 2048 uniform blocks (exactly resident capacity; uniform work by
// construction). Chunk-major/doc-minor ordering; each wave streams 16
// consecutive rows with a depth-2 software pipeline. No LDS, no sync.
__global__ __launch_bounds__(256) void dots_kernel(
    const float* __restrict__ hs,         // [B, T, D]
    const int*   __restrict__ clause_len, // [B, J]
    const float* __restrict__ fc_w,       // [D]
    const float* __restrict__ emo_w,      // [D]
    float*       __restrict__ ws_fc,      // [B, T]
    float*       __restrict__ ws_emo)     // [B, T]
{
    const int g     = blockIdx.x;
    const int b     = g & (NB - 1);
    const int chunk = g >> 5;
    const int lane  = threadIdx.x & 63;
    const int wave  = threadIdx.x >> 6;

    // weights first: issue these global loads before anything else
    const f4* fw4 = (const f4*)fc_w;
    const f4* ew4 = (const f4*)emo_w;
    const f4 wf0 = fw4[lane], wf1 = fw4[lane + 64], wf2 = fw4[lane + 128];
    const f4 we0 = ew4[lane], we1 = ew4[lane + 64], we2 = ew4[lane + 128];

    // L_b = used-token count of doc b
    int L = clause_len[(b << 6) + lane];
    #pragma unroll
    for (int s = 1; s < 64; s <<= 1) L += __shfl_xor(L, s, 64);

    const int r0 = chunk * CHUNK + (wave << 4);   // 16 consecutive rows per wave
    const int nr = min(16, L - r0);
    if (nr <= 0) return;

    const f4* r4  = (const f4*)(hs + ((size_t)b * TT + r0) * DD);
    float*    ofc = ws_fc  + b * TT + r0;
    float*    oem = ws_emo + b * TT + r0;

    if (nr == 16) {
        f4 a0 = r4[lane], a1 = r4[lane + 64], a2 = r4[lane + 128];
        #pragma unroll
        for (int i = 0; i < 16; ++i) {
            float pf, pe;
            if (i < 15) {
                const f4* n4 = r4 + (i + 1) * 192;
                const f4 b0 = n4[lane], b1 = n4[lane + 64], b2 = n4[lane + 128];
                dot_pair(a0, a1, a2, wf0, wf1, wf2, we0, we1, we2, pf, pe);
                reduce_pair(pf, pe);
                if (lane == 0) { ofc[i] = pf; oem[i] = pe; }
                a0 = b0; a1 = b1; a2 = b2;
            } else {
                dot_pair(a0, a1, a2, wf0, wf1, wf2, we0, we1, we2, pf, pe);
                reduce_pair(pf, pe);
                if (lane == 0) { ofc[i] = pf; oem[i] = pe; }
            }
        }
    } else {
        for (int i = 0; i < nr; ++i) {
            const f4* n4 = r4 + i * 192;
            const f4 a0 = n4[lane], a1 = n4[lane + 64], a2 = n4[lane + 128];
            float pf, pe;
            dot_pair(a0, a1, a2, wf0, wf1, wf2, we0, we1, we2, pf, pe);
            reduce_pair(pf, pe);
            if (lane == 0) { ofc[i] = pf; oem[i] = pe; }
        }
    }
}

// ---------------- Phase 2: per-clause softmax + sigmoid -------------------
__global__ __launch_bounds__(256) void pool_kernel(
    const int*   __restrict__ clause_len, // [B, J]
    const float* __restrict__ ws_fc,      // [B, T]
    const float* __restrict__ ws_emo,     // [B, T]
    const float* __restrict__ fc_b,       // [1]
    const float* __restrict__ emo_b,      // [1]
    float*       __restrict__ out)        // [B, J]
{
    const int lane = threadIdx.x & 63;
    const int wave = threadIdx.x >> 6;
    const int bj   = (blockIdx.x << 2) + wave;
    const int b    = bj >> 6;
    const int j    = bj & 63;

    const int cl   = clause_len[(b << 6) + lane];
    const int clen = __shfl(cl, j, 64);
    int pre = (lane < j) ? cl : 0;
    #pragma unroll
    for (int s = 1; s < 64; s <<= 1) pre += __shfl_xor(pre, s, 64);
    const int start = pre;

    const bool valid = lane < clen;
    const int  t     = b * TT + start + lane;
    float v   = valid ? (ws_fc[t] + fc_b[0]) : -3.0e38f;
    float sem = valid ? ws_emo[t] : 0.0f;
    float m = v;
    #pragma unroll
    for (int s = 1; s < 64; s <<= 1) m = fmaxf(m, __shfl_xor(m, s, 64));
    const float e = valid ? __expf(v - m) : 0.0f;
    float Z = e, S = e * sem;
    #pragma unroll
    for (int s = 1; s < 64; s <<= 1) {
        Z += __shfl_xor(Z, s, 64);
        S += __shfl_xor(S, s, 64);
    }
    if (lane == 0) {
        const float logit = S / Z + emo_b[0];
        out[bj] = 1.0f / (1.0f + __expf(-logit));
    }
}

extern "C" void kernel_launch(void* const* d_in, const int* in_sizes, int n_in,
                              void* d_out, int out_size, void* d_ws, size_t ws_size,
                              hipStream_t stream) {
    const float* hs         = (const float*)d_in[0];
    const int*   clause_len = (const int*)d_in[1];
    const float* fc_w       = (const float*)d_in[2];
    const float* fc_b       = (const float*)d_in[3];
    const float* emo_w      = (const float*)d_in[4];
    const float* emo_b      = (const float*)d_in[5];
    float* out = (float*)d_out;

    float* ws_fc  = (float*)d_ws;            // [B*T]
    float* ws_emo = ws_fc + NB * TT;         // [B*T]

    dots_kernel<<<NB * CPD, 256, 0, stream>>>(
        hs, clause_len, fc_w, emo_w, ws_fc, ws_emo);
    pool_kernel<<<NCLAUSES / 4, 256, 0, stream>>>(
        clause_len, ws_fc, ws_emo, fc_b, emo_b, out);
}

// Round 8
// 39.520 us; speedup vs baseline: 1.7384x; 1.0588x over previous
//
#include <hip/hip_runtime.h>

#define NB 32
#define TT 4096
#define DD 768
#define NJ 64
#define CHUNK 32
#define CPD (TT / CHUNK)          // 128 chunks per doc, grid 4096
#define NCLAUSES (NB * NJ)

typedef float f4 __attribute__((ext_vector_type(4)));

__device__ __forceinline__ void dot_pair(
    const f4 h0, const f4 h1, const f4 h2,
    const f4 wf0, const f4 wf1, const f4 wf2,
    const f4 we0, const f4 we1, const f4 we2,
    float& pf, float& pe)
{
    pf = h0.x * wf0.x;
    pf = fmaf(h0.y, wf0.y, pf); pf = fmaf(h0.z, wf0.z, pf); pf = fmaf(h0.w, wf0.w, pf);
    pf = fmaf(h1.x, wf1.x, pf); pf = fmaf(h1.y, wf1.y, pf);
    pf = fmaf(h1.z, wf1.z, pf); pf = fmaf(h1.w, wf1.w, pf);
    pf = fmaf(h2.x, wf2.x, pf); pf = fmaf(h2.y, wf2.y, pf);
    pf = fmaf(h2.z, wf2.z, pf); pf = fmaf(h2.w, wf2.w, pf);

    pe = h0.x * we0.x;
    pe = fmaf(h0.y, we0.y, pe); pe = fmaf(h0.z, we0.z, pe); pe = fmaf(h0.w, we0.w, pe);
    pe = fmaf(h1.x, we1.x, pe); pe = fmaf(h1.y, we1.y, pe);
    pe = fmaf(h1.z, we1.z, pe); pe = fmaf(h1.w, we1.w, pe);
    pe = fmaf(h2.x, we2.x, pe); pe = fmaf(h2.y, we2.y, pe);
    pe = fmaf(h2.z, we2.z, pe); pe = fmaf(h2.w, we2.w, pe);
}

__device__ __forceinline__ void reduce_pair(float& pf, float& pe)
{
    #pragma unroll
    for (int s = 1; s < 64; s <<= 1) {
        pf += __shfl_xor(pf, s, 64);
        pe += __shfl_xor(pe, s, 64);
    }
}

// ---------------- Phase 1: per-token dual dot-products --------------------
// R5 structure (CHUNK=32, chunk-major/doc-minor, 8 rows per wave), but ALL
// 8 rows' loads (24 x dwordx4 per lane = 24 KB per wave) are issued before
// any compute: forces deep MLP the compiler was collapsing at VGPR=40.
__global__ __launch_bounds__(256) void dots_kernel(
    const float* __restrict__ hs,         // [B, T, D]
    const int*   __restrict__ clause_len, // [B, J]
    const float* __restrict__ fc_w,       // [D]
    const float* __restrict__ emo_w,      // [D]
    float*       __restrict__ ws_fc,      // [B, T]
    float*       __restrict__ ws_emo)     // [B, T]
{
    const int g     = blockIdx.x;
    const int b     = g & (NB - 1);
    const int chunk = g >> 5;
    const int lane  = threadIdx.x & 63;
    const int wave  = threadIdx.x >> 6;

    // L_b = used-token count of doc b
    int L = clause_len[(b << 6) + lane];
    #pragma unroll
    for (int s = 1; s < 64; s <<= 1) L += __shfl_xor(L, s, 64);

    const int r0 = chunk * CHUNK + (wave << 3);   // 8 consecutive rows per wave
    const int nr = min(8, L - r0);
    if (nr <= 0) return;

    const f4* fw4 = (const f4*)fc_w;
    const f4* ew4 = (const f4*)emo_w;

    const f4* r4  = (const f4*)(hs + ((size_t)b * TT + r0) * DD);
    float*    ofc = ws_fc  + b * TT + r0;
    float*    oem = ws_emo + b * TT + r0;

    if (nr == 8) {
        // Issue ALL row loads first (fully unrolled -> constant indices ->
        // registers; 24 outstanding dwordx4 per lane).
        f4 A[8][3];
        #pragma unroll
        for (int i = 0; i < 8; ++i) {
            const f4* p = r4 + i * 192;
            A[i][0] = p[lane];
            A[i][1] = p[lane + 64];
            A[i][2] = p[lane + 128];
        }
        // Weights after the streaming loads (L2-hit, short latency).
        const f4 wf0 = fw4[lane], wf1 = fw4[lane + 64], wf2 = fw4[lane + 128];
        const f4 we0 = ew4[lane], we1 = ew4[lane + 64], we2 = ew4[lane + 128];
        #pragma unroll
        for (int i = 0; i < 8; ++i) {
            float pf, pe;
            dot_pair(A[i][0], A[i][1], A[i][2], wf0, wf1, wf2, we0, we1, we2, pf, pe);
            reduce_pair(pf, pe);
            if (lane == 0) { ofc[i] = pf; oem[i] = pe; }
        }
    } else {
        const f4 wf0 = fw4[lane], wf1 = fw4[lane + 64], wf2 = fw4[lane + 128];
        const f4 we0 = ew4[lane], we1 = ew4[lane + 64], we2 = ew4[lane + 128];
        for (int i = 0; i < nr; ++i) {
            const f4* p = r4 + i * 192;
            const f4 a0 = p[lane], a1 = p[lane + 64], a2 = p[lane + 128];
            float pf, pe;
            dot_pair(a0, a1, a2, wf0, wf1, wf2, we0, we1, we2, pf, pe);
            reduce_pair(pf, pe);
            if (lane == 0) { ofc[i] = pf; oem[i] = pe; }
        }
    }
}

// ---------------- Phase 2: per-clause softmax + sigmoid -------------------
__global__ __launch_bounds__(256) void pool_kernel(
    const int*   __restrict__ clause_len, // [B, J]
    const float* __restrict__ ws_fc,      // [B, T]
    const float* __restrict__ ws_emo,     // [B, T]
    const float* __restrict__ fc_b,       // [1]
    const float* __restrict__ emo_b,      // [1]
    float*       __restrict__ out)        // [B, J]
{
    const int lane = threadIdx.x & 63;
    const int wave = threadIdx.x >> 6;
    const int bj   = (blockIdx.x << 2) + wave;
    const int b    = bj >> 6;
    const int j    = bj & 63;

    const int cl   = clause_len[(b << 6) + lane];
    const int clen = __shfl(cl, j, 64);
    int pre = (lane < j) ? cl : 0;
    #pragma unroll
    for (int s = 1; s < 64; s <<= 1) pre += __shfl_xor(pre, s, 64);
    const int start = pre;

    const bool valid = lane < clen;
    const int  t     = b * TT + start + lane;
    float v   = valid ? (ws_fc[t] + fc_b[0]) : -3.0e38f;
    float sem = valid ? ws_emo[t] : 0.0f;
    float m = v;
    #pragma unroll
    for (int s = 1; s < 64; s <<= 1) m = fmaxf(m, __shfl_xor(m, s, 64));
    const float e = valid ? __expf(v - m) : 0.0f;
    float Z = e, S = e * sem;
    #pragma unroll
    for (int s = 1; s < 64; s <<= 1) {
        Z += __shfl_xor(Z, s, 64);
        S += __shfl_xor(S, s, 64);
    }
    if (lane == 0) {
        const float logit = S / Z + emo_b[0];
        out[bj] = 1.0f / (1.0f + __expf(-logit));
    }
}

extern "C" void kernel_launch(void* const* d_in, const int* in_sizes, int n_in,
                              void* d_out, int out_size, void* d_ws, size_t ws_size,
                              hipStream_t stream) {
    const float* hs         = (const float*)d_in[0];
    const int*   clause_len = (const int*)d_in[1];
    const float* fc_w       = (const float*)d_in[2];
    const float* fc_b       = (const float*)d_in[3];
    const float* emo_w      = (const float*)d_in[4];
    const float* emo_b      = (const float*)d_in[5];
    float* out = (float*)d_out;

    float* ws_fc  = (float*)d_ws;            // [B*T]
    float* ws_emo = ws_fc + NB * TT;         // [B*T]

    dots_kernel<<<NB * CPD, 256, 0, stream>>>(
        hs, clause_len, fc_w, emo_w, ws_fc, ws_emo);
    pool_kernel<<<NCLAUSES / 4, 256, 0, stream>>>(
        clause_len, ws_fc, ws_emo, fc_b, emo_b, out);
}